// Round 8
// baseline (279.762 us; speedup 1.0000x reference)
//
#include <hip/hip_runtime.h>

#define NN  6144
#define ICH 256
#define OCH 128
#define QW  160    // per-row edge cap (Poisson mean 61.4, sd 7.8; 160 = 12+ sigma)

typedef float vf4 __attribute__((ext_vector_type(4)));

// ---------------------------------------------------------------------------
// K1: ft[n][o] = sum_k W[o,k] * x[k,n]  (transposed: per-edge gather reads one
// contiguous 512B row). Epilogue fuses f1/f2 = w1/w2 . ft[n].
// ---------------------------------------------------------------------------
__global__ __launch_bounds__(256) void k_fts(const float* __restrict__ x,
        const float* __restrict__ W, const float* __restrict__ w1,
        const float* __restrict__ w2, float* __restrict__ ft,
        float* __restrict__ f1, float* __restrict__ f2) {
    __shared__ float xs[32][32];        // [kk][nn]
    __shared__ float Ws[32][OCH + 4];   // [kk][o]
    const int n0  = blockIdx.x * 32;
    const int tid = threadIdx.x;
    const int oq = (tid & 31) * 4;      // thread's 4 o's
    const int nq = (tid >> 5) * 4;      // thread's 4 n's
    float acc[4][4] = {};
    for (int k0 = 0; k0 < ICH; k0 += 32) {
        __syncthreads();
        {   // stage x tile: 32k x 32n
            const int nn = tid & 31;
            const int kb = tid >> 5;    // 0..7
#pragma unroll
            for (int r = 0; r < 4; ++r)
                xs[kb + r * 8][nn] = x[(size_t)(k0 + kb + r * 8) * NN + n0 + nn];
        }
        {   // stage W tile: 32k x 128o
            const int kk = tid & 31;
            const int ob = tid >> 5;    // 0..7
#pragma unroll
            for (int r = 0; r < 16; ++r) {
                const int o = ob + r * 8;
                Ws[kk][o] = W[o * ICH + k0 + kk];  // coalesced over k
            }
        }
        __syncthreads();
#pragma unroll
        for (int kk = 0; kk < 32; ++kk) {
            const float4 xv = *(const float4*)&xs[kk][nq];
            const float4 wv = *(const float4*)&Ws[kk][oq];
            const float xa[4] = {xv.x, xv.y, xv.z, xv.w};
            const float wa[4] = {wv.x, wv.y, wv.z, wv.w};
#pragma unroll
            for (int a = 0; a < 4; ++a)
#pragma unroll
                for (int b = 0; b < 4; ++b)
                    acc[a][b] = fmaf(xa[a], wa[b], acc[a][b]);
        }
    }
#pragma unroll
    for (int a = 0; a < 4; ++a) {
        float4 v = make_float4(acc[a][0], acc[a][1], acc[a][2], acc[a][3]);
        *(float4*)&ft[(size_t)(n0 + nq + a) * OCH + oq] = v;
    }
    // ---- fused f1/f2 epilogue: this block holds ALL 128 o for its 32 n ----
    const float4 w1v = *(const float4*)(w1 + oq);
    const float4 w2v = *(const float4*)(w2 + oq);
    float p1[4], p2[4];
#pragma unroll
    for (int a = 0; a < 4; ++a) {
        p1[a] = acc[a][0] * w1v.x + acc[a][1] * w1v.y + acc[a][2] * w1v.z + acc[a][3] * w1v.w;
        p2[a] = acc[a][0] * w2v.x + acc[a][1] * w2v.y + acc[a][2] * w2v.z + acc[a][3] * w2v.w;
    }
#pragma unroll
    for (int m = 16; m > 0; m >>= 1) {
#pragma unroll
        for (int a = 0; a < 4; ++a) {
            p1[a] += __shfl_xor(p1[a], m);
            p2[a] += __shfl_xor(p2[a], m);
        }
    }
    if ((tid & 31) == 0) {
#pragma unroll
        for (int a = 0; a < 4; ++a) {
            f1[n0 + nq + a] = p1[a];
            f2[n0 + nq + a] = p2[a];
        }
    }
}

// ---------------------------------------------------------------------------
// K2 (k_row): ONE WAVE PER ROW, whole row staged to LDS via global_load_lds
// DMA (24 x 1KB ops, fire-and-forget — bypasses the VGPR return path that
// capped every prior shape at ~2 TB/s). After the drain, everything runs from
// LDS/L2: bit-pack -> ballot decode (~9 iters) -> exp/den -> half-wave-per-
// edge float4 ft gathers -> strided out write. 2 waves/block, 51KB LDS ->
// 3 blocks/CU, 144KB of DMA in flight per CU.
// ---------------------------------------------------------------------------
__global__ __launch_bounds__(128) void k_row(const float* __restrict__ adj,
        const float* __restrict__ ft, const float* __restrict__ f1,
        const float* __restrict__ f2, const float* __restrict__ b1,
        const float* __restrict__ b2, const float* __restrict__ vb,
        float* __restrict__ out) {
    __shared__ float  rowbuf[2][NN];     // 48 KB: one full adj row per wave
    __shared__ float2 q[2][QW];          // per-wave (j, e) edge queue
    const int tid  = threadIdx.x;
    const int lane = tid & 63;
    const int wave = tid >> 6;
    const int i = blockIdx.x * 2 + wave;
    const float* arow = adj + (size_t)i * NN;
    // ---- stage: 24 independent 1KB DMAs (lane l -> ldsbase + l*16, linear) --
#pragma unroll
    for (int w = 0; w < 24; ++w) {
        __builtin_amdgcn_global_load_lds(
            (const __attribute__((address_space(1))) void*)(arow + w * 256 + lane * 4),
            (__attribute__((address_space(3))) void*)(&rowbuf[wave][w * 256]),
            16, 0, 0);
    }
    const float s1 = f1[i] + b1[0] + b2[0];     // overlaps with DMA flight
    __syncthreads();                            // vmcnt drain + LDS visibility
    // ---- scan from LDS: pack 32 bits/lane per g-group, ballot-decode -------
    const unsigned long long lt = (1ull << lane) - 1;
    float2* qw = q[wave];
    float den = 0.f;
    int cnt = 0;                                // wave-uniform by construction
#pragma unroll
    for (int g = 0; g < 3; ++g) {
        unsigned w = 0;
#pragma unroll
        for (int k = 0; k < 8; ++k) {
            const vf4 a4 = *(const vf4*)&rowbuf[wave][g * 2048 + k * 256 + lane * 4];
            w |= (a4.x != 0.f ? 1u : 0u) << (4 * k);
            w |= (a4.y != 0.f ? 2u : 0u) << (4 * k);
            w |= (a4.z != 0.f ? 4u : 0u) << (4 * k);
            w |= (a4.w != 0.f ? 8u : 0u) << (4 * k);
        }
        for (;;) {                              // ~3 iters (max bits per lane)
            const unsigned long long act = __ballot(w != 0);
            if (!act) break;
            if (w) {
                const int b = __builtin_ctz(w);
                w &= w - 1;
                const int j = g * 2048 + (b >> 2) * 256 + lane * 4 + (b & 3);
                float s = s1 + f2[j];           // f2: 24KB, L1/L2-resident
                s = s > 0.f ? s : 0.2f * s;
                const float e = __expf(s);
                den += e;
                const int slot = cnt + (int)__popcll(act & lt);
                if (slot < QW)
                    qw[slot] = make_float2(__int_as_float(j), e);
            }
            cnt += (int)__popcll(act);
        }
    }
#pragma unroll
    for (int off = 32; off > 0; off >>= 1) den += __shfl_xor(den, off);
    const float inv = 1.f / den;
    const int nE = cnt < QW ? cnt : QW;
    // ---- gather: half-wave per edge, lane owns channels 4l..4l+3 -----------
    const int half = lane >> 5;
    const int c0 = (lane & 31) * 4;
    float4 nm = make_float4(0.f, 0.f, 0.f, 0.f);
#pragma unroll 4
    for (int idx = half; idx < nE; idx += 2) {  // 2 edges per wave-iter
        const float2 pe = qw[idx];              // half-wave LDS broadcast
        const int   j = __float_as_int(pe.x);
        const float e = pe.y;
        const float4 g4 = *(const float4*)(ft + (size_t)j * OCH + c0);
        nm.x = fmaf(e, g4.x, nm.x);
        nm.y = fmaf(e, g4.y, nm.y);
        nm.z = fmaf(e, g4.z, nm.z);
        nm.w = fmaf(e, g4.w, nm.w);
    }
    nm.x += __shfl_xor(nm.x, 32);               // fold odd-edge half in
    nm.y += __shfl_xor(nm.y, 32);
    nm.z += __shfl_xor(nm.z, 32);
    nm.w += __shfl_xor(nm.w, 32);
    if (half == 0) {
        const float4 bv = *(const float4*)(vb + (size_t)i * OCH + c0);
        // out[0, c, i] = vals[i, c] + vars_bias[0, i, c]
        out[(size_t)(c0    ) * NN + i] = fmaf(nm.x, inv, bv.x);
        out[(size_t)(c0 + 1) * NN + i] = fmaf(nm.y, inv, bv.y);
        out[(size_t)(c0 + 2) * NN + i] = fmaf(nm.z, inv, bv.z);
        out[(size_t)(c0 + 3) * NN + i] = fmaf(nm.w, inv, bv.w);
    }
}

// ---------------------------------------------------------------------------
extern "C" void kernel_launch(void* const* d_in, const int* in_sizes, int n_in,
                              void* d_out, int out_size, void* d_ws, size_t ws_size,
                              hipStream_t stream) {
    const float* x   = (const float*)d_in[0];  // [1,256,6144]
    const float* adj = (const float*)d_in[1];  // [6144,6144]
    const float* W   = (const float*)d_in[2];  // [128,256]
    const float* w1  = (const float*)d_in[3];  // [128]
    const float* b1  = (const float*)d_in[4];  // [1]
    const float* w2  = (const float*)d_in[5];  // [128]
    const float* b2  = (const float*)d_in[6];  // [1]
    const float* vb  = (const float*)d_in[7];  // [1,6144,128]
    float* out = (float*)d_out;                // [1,128,6144]

    char* ws = (char*)d_ws;
    float* ft = (float*)ws;                      // 3,145,728 B
    float* f1 = (float*)(ws + 3145728);          // 24,576 B
    float* f2 = (float*)(ws + 3145728 + 24576);  // 24,576 B

    k_fts<<<dim3(NN / 32), 256, 0, stream>>>(x, W, w1, w2, ft, f1, f2);
    k_row<<<dim3(NN / 2), 128, 0, stream>>>(adj, ft, f1, f2, b1, b2, vb, out);
}

// Round 9
// 257.190 us; speedup vs baseline: 1.0878x; 1.0878x over previous
//
#include <hip/hip_runtime.h>

#define NN  6144
#define ICH 256
#define OCH 128
#define QW  160    // per-row edge cap (Poisson mean 61.4, sd 7.8; 160 = 12 sigma)

typedef float vf4 __attribute__((ext_vector_type(4)));

// ---------------------------------------------------------------------------
// K1: ft[n][o] = sum_k W[o,k] * x[k,n]  (transposed: per-edge gather reads one
// contiguous 512B row). Epilogue fuses f1/f2 = w1/w2 . ft[n].
// ---------------------------------------------------------------------------
__global__ __launch_bounds__(256) void k_fts(const float* __restrict__ x,
        const float* __restrict__ W, const float* __restrict__ w1,
        const float* __restrict__ w2, float* __restrict__ ft,
        float* __restrict__ f1, float* __restrict__ f2) {
    __shared__ float xs[32][32];        // [kk][nn]
    __shared__ float Ws[32][OCH + 4];   // [kk][o]
    const int n0  = blockIdx.x * 32;
    const int tid = threadIdx.x;
    const int oq = (tid & 31) * 4;      // thread's 4 o's
    const int nq = (tid >> 5) * 4;      // thread's 4 n's
    float acc[4][4] = {};
    for (int k0 = 0; k0 < ICH; k0 += 32) {
        __syncthreads();
        {   // stage x tile: 32k x 32n
            const int nn = tid & 31;
            const int kb = tid >> 5;    // 0..7
#pragma unroll
            for (int r = 0; r < 4; ++r)
                xs[kb + r * 8][nn] = x[(size_t)(k0 + kb + r * 8) * NN + n0 + nn];
        }
        {   // stage W tile: 32k x 128o
            const int kk = tid & 31;
            const int ob = tid >> 5;    // 0..7
#pragma unroll
            for (int r = 0; r < 16; ++r) {
                const int o = ob + r * 8;
                Ws[kk][o] = W[o * ICH + k0 + kk];  // coalesced over k
            }
        }
        __syncthreads();
#pragma unroll
        for (int kk = 0; kk < 32; ++kk) {
            const float4 xv = *(const float4*)&xs[kk][nq];
            const float4 wv = *(const float4*)&Ws[kk][oq];
            const float xa[4] = {xv.x, xv.y, xv.z, xv.w};
            const float wa[4] = {wv.x, wv.y, wv.z, wv.w};
#pragma unroll
            for (int a = 0; a < 4; ++a)
#pragma unroll
                for (int b = 0; b < 4; ++b)
                    acc[a][b] = fmaf(xa[a], wa[b], acc[a][b]);
        }
    }
#pragma unroll
    for (int a = 0; a < 4; ++a) {
        float4 v = make_float4(acc[a][0], acc[a][1], acc[a][2], acc[a][3]);
        *(float4*)&ft[(size_t)(n0 + nq + a) * OCH + oq] = v;
    }
    // ---- fused f1/f2 epilogue: this block holds ALL 128 o for its 32 n ----
    const float4 w1v = *(const float4*)(w1 + oq);
    const float4 w2v = *(const float4*)(w2 + oq);
    float p1[4], p2[4];
#pragma unroll
    for (int a = 0; a < 4; ++a) {
        p1[a] = acc[a][0] * w1v.x + acc[a][1] * w1v.y + acc[a][2] * w1v.z + acc[a][3] * w1v.w;
        p2[a] = acc[a][0] * w2v.x + acc[a][1] * w2v.y + acc[a][2] * w2v.z + acc[a][3] * w2v.w;
    }
#pragma unroll
    for (int m = 16; m > 0; m >>= 1) {
#pragma unroll
        for (int a = 0; a < 4; ++a) {
            p1[a] += __shfl_xor(p1[a], m);
            p2[a] += __shfl_xor(p2[a], m);
        }
    }
    if ((tid & 31) == 0) {
#pragma unroll
        for (int a = 0; a < 4; ++a) {
            f1[n0 + nq + a] = p1[a];
            f2[n0 + nq + a] = p2[a];
        }
    }
}

// ---------------------------------------------------------------------------
// K2 (k_attn): R4 structure (best measured) + XCD-affinity row mapping.
// One wave per row, 4 independent waves/block, register double-buffered adj
// stream, per-wave LDS queue, half-wave-per-edge float4 gather.
// Row map: blocks with equal (blockIdx%8) — same XCD under round-robin
// dispatch — own a CONTIGUOUS 768-row range, so each 128B line of `out`
// (32 consecutive i for one channel) is dirtied entirely within one XCD's
// L2 -> full-line writeback (kills the 5x write amplification), and each
// XCD streams a contiguous 18.9MB adj region (channel locality).
// ---------------------------------------------------------------------------
__global__ __launch_bounds__(256) void k_attn(const float* __restrict__ adj,
        const float* __restrict__ ft, const float* __restrict__ f1,
        const float* __restrict__ f2, const float* __restrict__ b1,
        const float* __restrict__ b2, const float* __restrict__ vb,
        float* __restrict__ out) {
    __shared__ float q_e[4][QW];
    __shared__ int   q_j[4][QW];
    __shared__ int   qc[4];
    const int tid  = threadIdx.x;
    const int lane = tid & 63;
    const int wave = tid >> 6;
    // XCD-affinity remap: r = XCD slot, q = position within its 768-row span
    const int i = (blockIdx.x & 7) * 768 + (blockIdx.x >> 3) * 4 + wave;
    if (lane == 0) qc[wave] = 0;     // same-wave program order: safe w/o barrier
    const float s1 = f1[i] + b1[0] + b2[0];
    const float* arow = adj + (size_t)i * NN;
    float den = 0.f;
    vf4 ab[2][6];
#pragma unroll
    for (int w = 0; w < 6; ++w)
        ab[0][w] = __builtin_nontemporal_load((const vf4*)(arow + lane * 4 + w * 256));
#pragma unroll
    for (int b = 0; b < 4; ++b) {
        if (b < 3) {
#pragma unroll
            for (int w = 0; w < 6; ++w)
                ab[(b + 1) & 1][w] = __builtin_nontemporal_load(
                    (const vf4*)(arow + (b + 1) * 1536 + lane * 4 + w * 256));
        }
#pragma unroll
        for (int w = 0; w < 6; ++w) {
            const vf4 a4 = ab[b & 1][w];
            const int j0 = b * 1536 + w * 256 + lane * 4;
            const int k = (a4.x != 0.f) + (a4.y != 0.f) + (a4.z != 0.f) + (a4.w != 0.f);
            if (k) {                                   // ~4% of lanes
                const float4 g = *(const float4*)(f2 + j0);
                int slot = atomicAdd(&qc[wave], k);    // private counter: no contention
                if (slot + k <= QW) {
                    if (a4.x != 0.f) { float s = s1 + g.x; s = s > 0.f ? s : 0.2f * s;
                                       float e = __expf(s); den += e;
                                       q_j[wave][slot] = j0;     q_e[wave][slot] = e; ++slot; }
                    if (a4.y != 0.f) { float s = s1 + g.y; s = s > 0.f ? s : 0.2f * s;
                                       float e = __expf(s); den += e;
                                       q_j[wave][slot] = j0 + 1; q_e[wave][slot] = e; ++slot; }
                    if (a4.z != 0.f) { float s = s1 + g.z; s = s > 0.f ? s : 0.2f * s;
                                       float e = __expf(s); den += e;
                                       q_j[wave][slot] = j0 + 2; q_e[wave][slot] = e; ++slot; }
                    if (a4.w != 0.f) { float s = s1 + g.w; s = s > 0.f ? s : 0.2f * s;
                                       float e = __expf(s); den += e;
                                       q_j[wave][slot] = j0 + 3; q_e[wave][slot] = e; }
                }
            }
        }
    }
#pragma unroll
    for (int off = 32; off > 0; off >>= 1) den += __shfl_xor(den, off);
    const float inv = 1.f / den;
    const int nE = qc[wave] < QW ? qc[wave] : QW;      // same-wave: ordered after atomics
    const int half = lane >> 5;
    const int c0 = (lane & 31) * 4;
    float4 nm = make_float4(0.f, 0.f, 0.f, 0.f);
#pragma unroll 2
    for (int idx = half; idx < nE; idx += 2) {         // 2 edges/wave-iter
        const int   j = q_j[wave][idx];                // half-wave LDS broadcast
        const float e = q_e[wave][idx];
        const float4 g = *(const float4*)(ft + (size_t)j * OCH + c0);
        nm.x = fmaf(e, g.x, nm.x);
        nm.y = fmaf(e, g.y, nm.y);
        nm.z = fmaf(e, g.z, nm.z);
        nm.w = fmaf(e, g.w, nm.w);
    }
    nm.x += __shfl_xor(nm.x, 32);                      // fold odd-edge half in
    nm.y += __shfl_xor(nm.y, 32);
    nm.z += __shfl_xor(nm.z, 32);
    nm.w += __shfl_xor(nm.w, 32);
    if (half == 0) {
        const float4 bv = *(const float4*)(vb + (size_t)i * OCH + c0);
        // out[0, c, i] = vals[i, c] + vars_bias[0, i, c]
        out[(size_t)(c0    ) * NN + i] = fmaf(nm.x, inv, bv.x);
        out[(size_t)(c0 + 1) * NN + i] = fmaf(nm.y, inv, bv.y);
        out[(size_t)(c0 + 2) * NN + i] = fmaf(nm.z, inv, bv.z);
        out[(size_t)(c0 + 3) * NN + i] = fmaf(nm.w, inv, bv.w);
    }
}

// ---------------------------------------------------------------------------
extern "C" void kernel_launch(void* const* d_in, const int* in_sizes, int n_in,
                              void* d_out, int out_size, void* d_ws, size_t ws_size,
                              hipStream_t stream) {
    const float* x   = (const float*)d_in[0];  // [1,256,6144]
    const float* adj = (const float*)d_in[1];  // [6144,6144]
    const float* W   = (const float*)d_in[2];  // [128,256]
    const float* w1  = (const float*)d_in[3];  // [128]
    const float* b1  = (const float*)d_in[4];  // [1]
    const float* w2  = (const float*)d_in[5];  // [128]
    const float* b2  = (const float*)d_in[6];  // [1]
    const float* vb  = (const float*)d_in[7];  // [1,6144,128]
    float* out = (float*)d_out;                // [1,128,6144]

    char* ws = (char*)d_ws;
    float* ft = (float*)ws;                      // 3,145,728 B
    float* f1 = (float*)(ws + 3145728);          // 24,576 B
    float* f2 = (float*)(ws + 3145728 + 24576);  // 24,576 B

    k_fts<<<dim3(NN / 32), 256, 0, stream>>>(x, W, w1, w2, ft, f1, f2);
    k_attn<<<dim3(NN / 4), 256, 0, stream>>>(adj, ft, f1, f2, b1, b2, vb, out);
}